// Round 1
// baseline (525.311 us; speedup 1.0000x reference)
//
#include <hip/hip_runtime.h>
#include <math.h>

#define NS 65536
#define DD 512
#define NF 32

// ---------------------------------------------------------------------------
// K0: u_hat[i] = u[i] + [(softplus(wtu)-1) - wtu] * w[i] / ||w[i]||^2  if wtu<1
// one block per flow, 256 threads
// ---------------------------------------------------------------------------
__global__ __launch_bounds__(256) void k_uhat(const float* __restrict__ u,
                                              const float* __restrict__ w,
                                              float* __restrict__ u_hat) {
    const int i = blockIdx.x;
    const int tid = threadIdx.x;
    __shared__ float s_wu[256];
    __shared__ float s_ww[256];
    float pu = 0.f, pw = 0.f;
    for (int d = tid; d < DD; d += 256) {
        float wv = w[i * DD + d];
        pu += wv * u[i * DD + d];
        pw += wv * wv;
    }
    s_wu[tid] = pu;
    s_ww[tid] = pw;
    __syncthreads();
    for (int s = 128; s > 0; s >>= 1) {
        if (tid < s) {
            s_wu[tid] += s_wu[tid + s];
            s_ww[tid] += s_ww[tid + s];
        }
        __syncthreads();
    }
    const float wtu = s_wu[0];
    const float ww  = s_ww[0];
    float scale = 0.f;
    if (wtu < 1.f) {
        float m = -1.f + log1pf(expf(wtu));   // softplus(wtu) - 1
        scale = (m - wtu) / ww;
    }
    for (int d = tid; d < DD; d += 256) {
        u_hat[i * DD + d] = u[i * DD + d] + scale * w[i * DD + d];
    }
}

// ---------------------------------------------------------------------------
// K0b: G[i][j] = dot(u_hat_i, w_j)   (wu_j = G[j][j])
// 1024 threads total, one dot each
// ---------------------------------------------------------------------------
__global__ __launch_bounds__(256) void k_gmat(const float* __restrict__ u_hat,
                                              const float* __restrict__ w,
                                              float* __restrict__ G) {
    const int tid = blockIdx.x * 256 + threadIdx.x;
    const int i = tid >> 5;
    const int j = tid & 31;
    const float* uh = u_hat + i * DD;
    const float* wj = w + j * DD;
    float s = 0.f;
    for (int d = 0; d < DD; ++d) s += uh[d] * wj[d];
    G[i * NF + j] = s;
}

// ---------------------------------------------------------------------------
// Main fused kernel: one thread per sample row.
//   lin_j = x.w_j + b_j + sum_{i<j} t_i G[i][j]
//   t_j = tanh(lin_j); logdet += log|1 + (1-t^2) G[j][j]|
//   out = x + sum_j t_j u_hat_j
// All flow params are wave-uniform -> scalar loads.
// ---------------------------------------------------------------------------
__global__ __launch_bounds__(256) void k_flow(const float* __restrict__ x,
                                              const float* __restrict__ w,
                                              const float* __restrict__ b,
                                              const float* __restrict__ u_hat,
                                              const float* __restrict__ G,
                                              float* __restrict__ out,
                                              float* __restrict__ logdet) {
    const int r = blockIdx.x * 256 + threadIdx.x;
    const float* xr = x + (size_t)r * DD;

    float lin[NF];
#pragma unroll
    for (int j = 0; j < NF; ++j) lin[j] = b[j];

    // Phase A: lin[j] += dot(x_row, w_j)
    for (int c = 0; c < DD; c += 16) {
        const float4 x0 = *(const float4*)(xr + c);
        const float4 x1 = *(const float4*)(xr + c + 4);
        const float4 x2 = *(const float4*)(xr + c + 8);
        const float4 x3 = *(const float4*)(xr + c + 12);
#pragma unroll
        for (int j = 0; j < NF; ++j) {
            const float* wj = w + j * DD + c;
            float acc;
            acc  = x0.x * wj[0]  + x0.y * wj[1]  + x0.z * wj[2]  + x0.w * wj[3];
            acc += x1.x * wj[4]  + x1.y * wj[5]  + x1.z * wj[6]  + x1.w * wj[7];
            acc += x2.x * wj[8]  + x2.y * wj[9]  + x2.z * wj[10] + x2.w * wj[11];
            acc += x3.x * wj[12] + x3.y * wj[13] + x3.z * wj[14] + x3.w * wj[15];
            lin[j] += acc;
        }
    }

    // Phase B: sequential recurrence over flows (t stored in place of lin)
    float ldet = 0.f;
#pragma unroll
    for (int j = 0; j < NF; ++j) {
        const float t = tanhf(lin[j]);
        const float det = 1.f + (1.f - t * t) * G[j * NF + j];
        ldet += logf(fabsf(det));
#pragma unroll
        for (int i = j + 1; i < NF; ++i) lin[i] += t * G[j * NF + i];
        lin[j] = t;
    }

    // Phase C: out = x + sum_j t_j * u_hat_j
    float* outr = out + (size_t)r * DD;
    for (int c = 0; c < DD; c += 8) {
        float4 a0 = *(const float4*)(xr + c);
        float4 a1 = *(const float4*)(xr + c + 4);
#pragma unroll
        for (int j = 0; j < NF; ++j) {
            const float* uj = u_hat + j * DD + c;
            const float t = lin[j];
            a0.x += t * uj[0]; a0.y += t * uj[1]; a0.z += t * uj[2]; a0.w += t * uj[3];
            a1.x += t * uj[4]; a1.y += t * uj[5]; a1.z += t * uj[6]; a1.w += t * uj[7];
        }
        *(float4*)(outr + c)     = a0;
        *(float4*)(outr + c + 4) = a1;
    }
    logdet[r] = ldet;
}

// ---------------------------------------------------------------------------
extern "C" void kernel_launch(void* const* d_in, const int* in_sizes, int n_in,
                              void* d_out, int out_size, void* d_ws, size_t ws_size,
                              hipStream_t stream) {
    const float* x = (const float*)d_in[0];
    const float* u = (const float*)d_in[1];
    const float* w = (const float*)d_in[2];
    const float* b = (const float*)d_in[3];

    float* out    = (float*)d_out;                 // [N, D]
    float* logdet = out + (size_t)NS * DD;         // [N]

    float* u_hat = (float*)d_ws;                   // NF*DD floats
    float* G     = u_hat + NF * DD;                // NF*NF floats

    k_uhat<<<NF, 256, 0, stream>>>(u, w, u_hat);
    k_gmat<<<(NF * NF) / 256, 256, 0, stream>>>(u_hat, w, G);
    k_flow<<<NS / 256, 256, 0, stream>>>(x, w, b, u_hat, G, out, logdet);
}

// Round 3
// 487.294 us; speedup vs baseline: 1.0780x; 1.0780x over previous
//
#include <hip/hip_runtime.h>
#include <math.h>

#define NS 65536
#define DD 512
#define NF 32

// ---------------------------------------------------------------------------
// K0a: u_hat[i] = u[i] + [(softplus(wtu)-1) - wtu] * w[i] / ||w[i]||^2 if wtu<1
// ---------------------------------------------------------------------------
__global__ __launch_bounds__(256) void k_uhat(const float* __restrict__ u,
                                              const float* __restrict__ w,
                                              float* __restrict__ u_hat) {
    const int i = blockIdx.x;
    const int tid = threadIdx.x;
    __shared__ float s_wu[256];
    __shared__ float s_ww[256];
    float pu = 0.f, pw = 0.f;
    for (int d = tid; d < DD; d += 256) {
        float wv = w[i * DD + d];
        pu += wv * u[i * DD + d];
        pw += wv * wv;
    }
    s_wu[tid] = pu;
    s_ww[tid] = pw;
    __syncthreads();
    for (int s = 128; s > 0; s >>= 1) {
        if (tid < s) {
            s_wu[tid] += s_wu[tid + s];
            s_ww[tid] += s_ww[tid + s];
        }
        __syncthreads();
    }
    const float wtu = s_wu[0];
    const float ww  = s_ww[0];
    float scale = 0.f;
    if (wtu < 1.f) {
        float m = -1.f + log1pf(expf(wtu));   // softplus(wtu) - 1
        scale = (m - wtu) / ww;
    }
    for (int d = tid; d < DD; d += 256) {
        u_hat[i * DD + d] = u[i * DD + d] + scale * w[i * DD + d];
    }
}

// ---------------------------------------------------------------------------
// K0b: G[i][j] = dot(u_hat_i, w_j)
// ---------------------------------------------------------------------------
__global__ __launch_bounds__(256) void k_gmat(const float* __restrict__ u_hat,
                                              const float* __restrict__ w,
                                              float* __restrict__ G) {
    const int tid = blockIdx.x * 256 + threadIdx.x;
    const int i = tid >> 5;
    const int j = tid & 31;
    const float* uh = u_hat + i * DD;
    const float* wj = w + j * DD;
    float s = 0.f;
    for (int d = 0; d < DD; ++d) s += uh[d] * wj[d];
    G[i * NF + j] = s;
}

// ---------------------------------------------------------------------------
// K1: LT[row][j] = dot(x_row, w_j)
// Block: 256 threads = 64 rows x 4 j-groups. x staged via swizzled LDS
// (coalesced global reads, conflict-spread ds_read_b128). w loads are
// wave-uniform -> scalar pipe.
// ---------------------------------------------------------------------------
#define KC 64  // k-chunk in floats

__global__ __launch_bounds__(256) void k_lin(const float* __restrict__ x,
                                             const float* __restrict__ w,
                                             float* __restrict__ LT) {
    __shared__ float xs[64 * KC];  // 16 KB, XOR-swizzled layout
    const int t  = threadIdx.x;
    const int jg = __builtin_amdgcn_readfirstlane(t >> 6);  // 0..3 (wave id)
    const int rl = t & 63;                                   // row within block
    const int r0 = blockIdx.x * 64;

    float acc[8];
#pragma unroll
    for (int jj = 0; jj < 8; ++jj) acc[jj] = 0.f;

    for (int kc = 0; kc < DD; kc += KC) {
        __syncthreads();  // protect previous chunk's reads
        // stage: 4096 floats, fully line-coalesced (16 lanes cover one row-chunk line pair)
#pragma unroll
        for (int i = 0; i < 4; ++i) {
            const int f   = i * 256 + t;
            const int row = f >> 4;   // 16 float4 per row-chunk
            const int c4  = f & 15;
            const float4 v = *(const float4*)(x + (size_t)(r0 + row) * DD + kc + c4 * 4);
            const int byte = row * 256 + ((c4 * 16) ^ ((row & 7) << 4));
            *(float4*)((char*)xs + byte) = v;
        }
        __syncthreads();
        // compute: this thread's row, 8 flows
#pragma unroll
        for (int c4 = 0; c4 < 16; ++c4) {
            const int byte = rl * 256 + ((c4 * 16) ^ ((rl & 7) << 4));
            const float4 xv = *(const float4*)((const char*)xs + byte);
#pragma unroll
            for (int jj = 0; jj < 8; ++jj) {
                const float* wp = w + (size_t)(jg * 8 + jj) * DD + kc + c4 * 4;  // uniform -> s_load
                acc[jj] += xv.x * wp[0] + xv.y * wp[1] + xv.z * wp[2] + xv.w * wp[3];
            }
        }
    }
    float* lp = LT + (size_t)(r0 + rl) * NF + jg * 8;
    *(float4*)(lp)     = make_float4(acc[0], acc[1], acc[2], acc[3]);
    *(float4*)(lp + 4) = make_float4(acc[4], acc[5], acc[6], acc[7]);
}

// ---------------------------------------------------------------------------
// K2: per-row recurrence. Reads LT (=lin partial), overwrites it with t=tanh.
// G/b loads are uniform -> scalar pipe. Thread per row.
// ---------------------------------------------------------------------------
__global__ __launch_bounds__(256) void k_rec(float* __restrict__ LT,
                                             const float* __restrict__ b,
                                             const float* __restrict__ G,
                                             float* __restrict__ logdet) {
    const int r = blockIdx.x * 256 + threadIdx.x;
    float* lp = LT + (size_t)r * NF;

    float lin[NF];
#pragma unroll
    for (int j = 0; j < NF; j += 4) {
        float4 v = *(const float4*)(lp + j);
        lin[j] = v.x + b[j]; lin[j+1] = v.y + b[j+1];
        lin[j+2] = v.z + b[j+2]; lin[j+3] = v.w + b[j+3];
    }

    float ldet = 0.f;
#pragma unroll
    for (int j = 0; j < NF; ++j) {
        const float tt = tanhf(lin[j]);
        const float gd = G[j * NF + j];
        ldet += logf(fabsf(1.f + (1.f - tt * tt) * gd));
#pragma unroll
        for (int i = j + 1; i < NF; ++i) lin[i] = fmaf(tt, G[j * NF + i], lin[i]);
        lin[j] = tt;
    }

#pragma unroll
    for (int j = 0; j < NF; j += 4) {
        *(float4*)(lp + j) = make_float4(lin[j], lin[j+1], lin[j+2], lin[j+3]);
    }
    logdet[r] = ldet;
}

// ---------------------------------------------------------------------------
// K3: out[r][c] = x[r][c] + sum_j t[r][j] * u_hat[j][c]
// Wave owns 256 columns (lane*4) x 32 rows. u_hat tile in 128 VGPRs,
// t loads wave-uniform -> SGPR. All global x/out accesses are 1KB bursts.
// ---------------------------------------------------------------------------
#define OUT_R 32

__global__ __launch_bounds__(256) void k_out(const float* __restrict__ x,
                                             const float* __restrict__ u_hat,
                                             const float* __restrict__ T,
                                             float* __restrict__ out) {
    const int wid  = __builtin_amdgcn_readfirstlane(blockIdx.x * 4 + (threadIdx.x >> 6));
    const int lane = threadIdx.x & 63;
    const int cg   = wid & 1;          // column half
    const int rg   = wid >> 1;         // row group
    const int col  = cg * 256 + lane * 4;

    float4 uh[NF];
#pragma unroll
    for (int j = 0; j < NF; ++j) uh[j] = *(const float4*)(u_hat + (size_t)j * DD + col);

    for (int rr = 0; rr < OUT_R; ++rr) {
        const int r = rg * OUT_R + rr;
        float4 o = *(const float4*)(x + (size_t)r * DD + col);
#pragma unroll
        for (int j = 0; j < NF; ++j) {
            const float tj = T[(size_t)r * NF + j];  // uniform -> s_load
            o.x = fmaf(tj, uh[j].x, o.x);
            o.y = fmaf(tj, uh[j].y, o.y);
            o.z = fmaf(tj, uh[j].z, o.z);
            o.w = fmaf(tj, uh[j].w, o.w);
        }
        *(float4*)(out + (size_t)r * DD + col) = o;
    }
}

// ---------------------------------------------------------------------------
// Fallback (round-1 monolith) in case ws_size is too small for LT.
// ---------------------------------------------------------------------------
__global__ __launch_bounds__(256) void k_flow(const float* __restrict__ x,
                                              const float* __restrict__ w,
                                              const float* __restrict__ b,
                                              const float* __restrict__ u_hat,
                                              const float* __restrict__ G,
                                              float* __restrict__ out,
                                              float* __restrict__ logdet) {
    const int r = blockIdx.x * 256 + threadIdx.x;
    const float* xr = x + (size_t)r * DD;
    float lin[NF];
#pragma unroll
    for (int j = 0; j < NF; ++j) lin[j] = b[j];
    for (int c = 0; c < DD; c += 16) {
        const float4 x0 = *(const float4*)(xr + c);
        const float4 x1 = *(const float4*)(xr + c + 4);
        const float4 x2 = *(const float4*)(xr + c + 8);
        const float4 x3 = *(const float4*)(xr + c + 12);
#pragma unroll
        for (int j = 0; j < NF; ++j) {
            const float* wj = w + j * DD + c;
            float acc;
            acc  = x0.x * wj[0]  + x0.y * wj[1]  + x0.z * wj[2]  + x0.w * wj[3];
            acc += x1.x * wj[4]  + x1.y * wj[5]  + x1.z * wj[6]  + x1.w * wj[7];
            acc += x2.x * wj[8]  + x2.y * wj[9]  + x2.z * wj[10] + x2.w * wj[11];
            acc += x3.x * wj[12] + x3.y * wj[13] + x3.z * wj[14] + x3.w * wj[15];
            lin[j] += acc;
        }
    }
    float ldet = 0.f;
#pragma unroll
    for (int j = 0; j < NF; ++j) {
        const float t = tanhf(lin[j]);
        const float det = 1.f + (1.f - t * t) * G[j * NF + j];
        ldet += logf(fabsf(det));
#pragma unroll
        for (int i = j + 1; i < NF; ++i) lin[i] += t * G[j * NF + i];
        lin[j] = t;
    }
    float* outr = out + (size_t)r * DD;
    for (int c = 0; c < DD; c += 8) {
        float4 a0 = *(const float4*)(xr + c);
        float4 a1 = *(const float4*)(xr + c + 4);
#pragma unroll
        for (int j = 0; j < NF; ++j) {
            const float* uj = u_hat + j * DD + c;
            const float t = lin[j];
            a0.x += t * uj[0]; a0.y += t * uj[1]; a0.z += t * uj[2]; a0.w += t * uj[3];
            a1.x += t * uj[4]; a1.y += t * uj[5]; a1.z += t * uj[6]; a1.w += t * uj[7];
        }
        *(float4*)(outr + c)     = a0;
        *(float4*)(outr + c + 4) = a1;
    }
    logdet[r] = ldet;
}

// ---------------------------------------------------------------------------
extern "C" void kernel_launch(void* const* d_in, const int* in_sizes, int n_in,
                              void* d_out, int out_size, void* d_ws, size_t ws_size,
                              hipStream_t stream) {
    const float* x = (const float*)d_in[0];
    const float* u = (const float*)d_in[1];
    const float* w = (const float*)d_in[2];
    const float* b = (const float*)d_in[3];

    float* out    = (float*)d_out;             // [N, D]
    float* logdet = out + (size_t)NS * DD;     // [N]

    float* u_hat = (float*)d_ws;               // NF*DD
    float* G     = u_hat + NF * DD;            // NF*NF
    float* LT    = G + NF * NF;                // NS*NF (lin, then t in-place)

    const size_t need = (size_t)(NF * DD + NF * NF + (size_t)NS * NF) * sizeof(float);

    k_uhat<<<NF, 256, 0, stream>>>(u, w, u_hat);
    k_gmat<<<(NF * NF) / 256, 256, 0, stream>>>(u_hat, w, G);

    if (ws_size >= need) {
        k_lin<<<NS / 64, 256, 0, stream>>>(x, w, LT);
        k_rec<<<NS / 256, 256, 0, stream>>>(LT, b, G, logdet);
        k_out<<<(NS / OUT_R) * 2 / 4, 256, 0, stream>>>(x, u_hat, LT, out);
    } else {
        k_flow<<<NS / 256, 256, 0, stream>>>(x, w, b, u_hat, G, out, logdet);
    }
}